// Round 2
// baseline (340.490 us; speedup 1.0000x reference)
//
#include <hip/hip_runtime.h>
#include <cstdint>
#include <cstddef>

// ---------------------------------------------------------------------------
// Differential attention forward, MI355X/gfx950.
// Pipeline: x->bf16 | Wqkv,Wproj -> bf16 transposed | qkv GEMM (bf16 MFMA) |
//           fused flash diff-attn + RMSNorm | proj GEMM (fp32 out).
// All matmuls: mfma_f32_16x16x32_bf16, fp32 accumulate.
// Fragment layouts (m89/m91-verified): A[m=l&15][k=(l>>4)*8+e],
// B[k=(l>>4)*8+e][n=l&15], C row=(l>>4)*4+reg, col=l&15.
// R1 changes: V^T LDS write XOR-swizzle (was 16-way conflicted), V-frags
// hoisted to regs shared across both branches, yb aliases xb (ws 40MB).
// ---------------------------------------------------------------------------

typedef short bf16x8 __attribute__((ext_vector_type(8)));
typedef float f32x4  __attribute__((ext_vector_type(4)));
typedef unsigned short u16;
typedef u16 u16x4v __attribute__((ext_vector_type(4)));

#define LAMBDA_INIT 0.35550906759096926f
#define ONE_MINUS_LAMBDA_INIT 0.6444909324090307f
#define SCORE_SCALE 0.17677669529663687f   // 1/sqrt(32)

__device__ __forceinline__ u16 f2bf(float f) {
  uint32_t u = __float_as_uint(f);
  u += 0x7fffu + ((u >> 16) & 1u);          // round-to-nearest-even
  return (u16)(u >> 16);
}

__device__ __forceinline__ void gload_lds16(const void* g, void* lds) {
  // async global->LDS, 16B per lane; LDS dest = uniform base + lane*16
  __builtin_amdgcn_global_load_lds(
      (const __attribute__((address_space(1))) void*)g,
      (__attribute__((address_space(3))) void*)lds, 16, 0, 0);
}

__device__ __forceinline__ f32x4 vmax4(f32x4 a, f32x4 b) {
  f32x4 r;
#pragma unroll
  for (int i = 0; i < 4; ++i) r[i] = fmaxf(a[i], b[i]);
  return r;
}

__device__ __forceinline__ f32x4 vshfl_xor(f32x4 v, int m) {
  f32x4 r;
#pragma unroll
  for (int i = 0; i < 4; ++i) r[i] = __shfl_xor(v[i], m, 64);
  return r;
}

// ---------------------------------------------------------------------------
// elementwise fp32 -> bf16 (x)
// ---------------------------------------------------------------------------
__global__ void conv_x_kernel(const float* __restrict__ in, u16* __restrict__ out, int n4) {
  int i = blockIdx.x * blockDim.x + threadIdx.x;
  if (i < n4) {
    float4 v = ((const float4*)in)[i];
    u16x4v o;
    o.x = f2bf(v.x); o.y = f2bf(v.y); o.z = f2bf(v.z); o.w = f2bf(v.w);
    ((u16x4v*)out)[i] = o;
  }
}

// ---------------------------------------------------------------------------
// W [K][N] fp32 -> WT [N][K] bf16 (64x64 LDS tile transpose)
// ---------------------------------------------------------------------------
__global__ void conv_transpose_kernel(const float* __restrict__ W, u16* __restrict__ WT,
                                      int K, int N) {
  __shared__ u16 L[64][72];
  const int n0 = blockIdx.x * 64, k0 = blockIdx.y * 64;
#pragma unroll
  for (int i = 0; i < 16; ++i) {
    int lin = i * 256 + threadIdx.x;
    int rr = lin >> 6, cc = lin & 63;
    L[rr][cc] = f2bf(W[(size_t)(k0 + rr) * N + n0 + cc]);
  }
  __syncthreads();
#pragma unroll
  for (int i = 0; i < 16; ++i) {
    int lin = i * 256 + threadIdx.x;
    int rr = lin >> 6, cc = lin & 63;        // rr = out row (n), cc = out col (k)
    WT[(size_t)(n0 + rr) * K + k0 + cc] = L[cc][rr];
  }
}

// ---------------------------------------------------------------------------
// bt-GEMM: C[M][N] = A[M][K] * Bt[N][K]^T, bf16 in, OutT out (m97 structure:
// 128x128 tile, BK=32, 4 waves 2x2 of 64x64, global_load_lds w=16, dbuf LDS,
// one barrier per K-step). T2-swizzle deliberately NOT applied: regime-gate
// says swizzle is null on 2-phase structures (m228d/m230).
// ---------------------------------------------------------------------------
template <typename OutT>
__global__ __launch_bounds__(256, 2) void gemm_bt(const u16* __restrict__ A,
                                                  const u16* __restrict__ Bt,
                                                  OutT* __restrict__ C,
                                                  int M, int N, int K) {
  __shared__ __align__(16) u16 As[2][128 * 32];
  __shared__ __align__(16) u16 Bs[2][128 * 32];
  const int wid = threadIdx.x >> 6, lane = threadIdx.x & 63;
  const int l15 = lane & 15, lhi = lane >> 4;
  const int wm = wid >> 1, wn = wid & 1;
  const int tm = blockIdx.x * 128, tn = blockIdx.y * 128;
  const int rr = lane >> 2, cb = (lane & 3) * 8;
  const int nkt = K >> 5;

  f32x4 acc[4][4];
#pragma unroll
  for (int m = 0; m < 4; ++m)
#pragma unroll
    for (int n = 0; n < 4; ++n) acc[m][n] = (f32x4){0.f, 0.f, 0.f, 0.f};

  auto stage = [&](int buf, int kt) {
#pragma unroll
    for (int i = 0; i < 2; ++i) {
      int lr = wid * 32 + i * 16;
      gload_lds16(A + (size_t)(tm + lr + rr) * K + kt * 32 + cb, &As[buf][lr * 32]);
      gload_lds16(Bt + (size_t)(tn + lr + rr) * K + kt * 32 + cb, &Bs[buf][lr * 32]);
    }
  };

  stage(0, 0);
  __syncthreads();
  int buf = 0;
  for (int kt = 0; kt < nkt; ++kt) {
    if (kt + 1 < nkt) stage(buf ^ 1, kt + 1);
    bf16x8 af[4], bfr[4];
#pragma unroll
    for (int m = 0; m < 4; ++m)
      af[m] = *(const bf16x8*)&As[buf][(wm * 64 + m * 16 + l15) * 32 + lhi * 8];
#pragma unroll
    for (int n = 0; n < 4; ++n)
      bfr[n] = *(const bf16x8*)&Bs[buf][(wn * 64 + n * 16 + l15) * 32 + lhi * 8];
#pragma unroll
    for (int m = 0; m < 4; ++m)
#pragma unroll
      for (int n = 0; n < 4; ++n)
        acc[m][n] = __builtin_amdgcn_mfma_f32_16x16x32_bf16(af[m], bfr[n], acc[m][n], 0, 0, 0);
    __syncthreads();
    buf ^= 1;
  }

#pragma unroll
  for (int m = 0; m < 4; ++m)
#pragma unroll
    for (int n = 0; n < 4; ++n)
#pragma unroll
      for (int r = 0; r < 4; ++r) {
        int row = tm + wm * 64 + m * 16 + lhi * 4 + r;
        int col = tn + wn * 64 + n * 16 + l15;
        float v = acc[m][n][r];
        if constexpr (sizeof(OutT) == 2)
          C[(size_t)row * N + col] = (OutT)f2bf(v);
        else
          C[(size_t)row * N + col] = v;
      }
}

// ---------------------------------------------------------------------------
// Fused differential flash attention + RMSNorm.
// Grid: (T/64, B*H). Block: 256 threads = 4 waves, each wave owns 16 Q rows.
// qkv bf16 [B*T][3072]; y bf16 [B*T][1024] in [b,t,head*64+d] layout.
// V^T stored column-swizzled: element (n,k) lives at VTs[n][k ^ VSWZ(n)],
// VSWZ(n) = ((n>>3)&7)<<3. Involution (mask from row bits only); makes the
// 32 scalar u16 transpose-writes/thread conflict-free (was 16-way).
// ---------------------------------------------------------------------------
#define VSWZ(n) ((((n) >> 3) & 7) << 3)

__global__ __launch_bounds__(256, 2) void diff_attn_kernel(
    const u16* __restrict__ qkv,
    const float* __restrict__ lq1, const float* __restrict__ lk1,
    const float* __restrict__ lq2, const float* __restrict__ lk2,
    const float* __restrict__ rms_scale,
    u16* __restrict__ y) {
  __shared__ __align__(16) u16 K1s[128 * 32];
  __shared__ __align__(16) u16 K2s[128 * 32];
  __shared__ __align__(16) u16 VTs[64][136];     // V^T: [n=0..63][k-swizzled]
  __shared__ __align__(16) u16 Ps[4][16][136];   // per-wave P tile [16 m][128 k]

  const int wid = threadIdx.x >> 6, lane = threadIdx.x & 63;
  const int l15 = lane & 15, lhi = lane >> 4;
  const int qt = blockIdx.x;          // Q tile (64 rows)
  const int bh = blockIdx.y;          // b*16 + head
  const int b = bh >> 4, head = bh & 15;
  const size_t row0 = (size_t)b * 2048;

  // lambda scalar (uniform scalar loads, L2-resident; negligible)
  float d1 = 0.f, d2 = 0.f;
#pragma unroll
  for (int i = 0; i < 32; ++i) { d1 += lq1[i] * lk1[i]; d2 += lq2[i] * lk2[i]; }
  const float lam = expf(d1) - expf(d2) + LAMBDA_INIT;

  // Q fragments directly from global (A-frag layout == 16B contiguous rows)
  const u16* qb = qkv + (row0 + qt * 64 + wid * 16 + l15) * 3072;
  const bf16x8 q1 = *(const bf16x8*)(qb + head * 32 + lhi * 8);
  const bf16x8 q2 = *(const bf16x8*)(qb + 512 + head * 32 + lhi * 8);

  f32x4 o1[4], o2[4];
#pragma unroll
  for (int j = 0; j < 4; ++j) {
    o1[j] = (f32x4){0.f, 0.f, 0.f, 0.f};
    o2[j] = (f32x4){0.f, 0.f, 0.f, 0.f};
  }
  f32x4 mx1 = {-1e30f, -1e30f, -1e30f, -1e30f};
  f32x4 mx2 = {-1e30f, -1e30f, -1e30f, -1e30f};
  f32x4 ls1 = {0.f, 0.f, 0.f, 0.f}, ls2 = {0.f, 0.f, 0.f, 0.f};

  // online-softmax + PV for one branch; sf = 8 S frags (rows lhi*4+r, col j*16+l15)
  // vf = 16 hoisted V B-frags shared by both branches.
  auto branch = [&](f32x4* sf, const bf16x8* vf, f32x4& mx, f32x4& ls, f32x4* o) {
#pragma unroll
    for (int j = 0; j < 8; ++j) sf[j] *= SCORE_SCALE;
    f32x4 tmax = sf[0];
#pragma unroll
    for (int j = 1; j < 8; ++j) tmax = vmax4(tmax, sf[j]);
#pragma unroll
    for (int d = 1; d < 16; d <<= 1) tmax = vmax4(tmax, vshfl_xor(tmax, d));
    f32x4 mnew = vmax4(mx, tmax);
    f32x4 corr;
#pragma unroll
    for (int c = 0; c < 4; ++c) corr[c] = __expf(mx[c] - mnew[c]);
    mx = mnew;
    f32x4 rs = {0.f, 0.f, 0.f, 0.f};
#pragma unroll
    for (int j = 0; j < 8; ++j)
#pragma unroll
      for (int c = 0; c < 4; ++c) {
        float p = __expf(sf[j][c] - mnew[c]);
        sf[j][c] = p;
        rs[c] += p;
      }
#pragma unroll
    for (int d = 1; d < 16; d <<= 1) rs += vshfl_xor(rs, d);
    ls = ls * corr + rs;
#pragma unroll
    for (int j = 0; j < 4; ++j) o[j] *= corr;
    // P -> LDS (bf16), C-layout scatter
#pragma unroll
    for (int j = 0; j < 8; ++j)
#pragma unroll
      for (int c = 0; c < 4; ++c) Ps[wid][lhi * 4 + c][j * 16 + l15] = f2bf(sf[j][c]);
    asm volatile("s_waitcnt lgkmcnt(0)" ::: "memory");  // wave-local P visibility
    // PV: A = P [16][128], B = V [128][64] (V-frags pre-hoisted in vf)
#pragma unroll
    for (int s = 0; s < 4; ++s) {
      bf16x8 pa = *(const bf16x8*)&Ps[wid][l15][s * 32 + lhi * 8];
#pragma unroll
      for (int jn = 0; jn < 4; ++jn)
        o[jn] = __builtin_amdgcn_mfma_f32_16x16x32_bf16(pa, vf[s * 4 + jn], o[jn], 0, 0, 0);
    }
  };

  for (int kt = 0; kt < 16; ++kt) {
    // stage K1/K2 via global_load_lds (linear row-major [128][32])
    {
      const int sr = lane >> 2, cb = (lane & 3) * 8;
      const size_t grow = row0 + kt * 128;
#pragma unroll
      for (int i = 0; i < 2; ++i) {
        int lr = wid * 32 + i * 16;
        const u16* g1 = qkv + (grow + lr + sr) * 3072 + 1024 + head * 32 + cb;
        gload_lds16(g1, &K1s[lr * 32]);
        gload_lds16(g1 + 512, &K2s[lr * 32]);
      }
    }
    // stage V transposed (16B global loads, swizzled scalar u16 LDS writes —
    // conflict-free: banks = const + 4*(W^g) + (tr>>1), all-32 coverage)
    {
      const int tr = threadIdx.x >> 3, tc = (threadIdx.x & 7) * 8;
      const int sw = VSWZ(tc);                 // (tc+e)>>3 == tc>>3 for e<8
#pragma unroll
      for (int jj = 0; jj < 4; ++jj) {
        int vr = jj * 32 + tr;
        bf16x8 vv = *(const bf16x8*)(qkv + (row0 + kt * 128 + vr) * 3072 + 2048 + head * 64 + tc);
        int vrs = vr ^ sw;
#pragma unroll
        for (int e = 0; e < 8; ++e) VTs[tc + e][vrs] = (u16)vv[e];
      }
    }
    __syncthreads();

    // hoist V B-frags once, reuse in both branches
    bf16x8 vf[16];
#pragma unroll
    for (int s = 0; s < 4; ++s)
#pragma unroll
      for (int jn = 0; jn < 4; ++jn) {
        int vn = jn * 16 + l15;
        vf[s * 4 + jn] = *(const bf16x8*)&VTs[vn][(s * 32 + lhi * 8) ^ VSWZ(vn)];
      }

    {  // branch 1: S1 = Q1 K1^T
      f32x4 sf[8];
#pragma unroll
      for (int j = 0; j < 8; ++j) {
        bf16x8 kf = *(const bf16x8*)&K1s[(j * 16 + l15) * 32 + lhi * 8];
        sf[j] = __builtin_amdgcn_mfma_f32_16x16x32_bf16(q1, kf, (f32x4){0.f, 0.f, 0.f, 0.f}, 0, 0, 0);
      }
      branch(sf, vf, mx1, ls1, o1);
    }
    {  // branch 2: S2 = Q2 K2^T
      f32x4 sf[8];
#pragma unroll
      for (int j = 0; j < 8; ++j) {
        bf16x8 kf = *(const bf16x8*)&K2s[(j * 16 + l15) * 32 + lhi * 8];
        sf[j] = __builtin_amdgcn_mfma_f32_16x16x32_bf16(q2, kf, (f32x4){0.f, 0.f, 0.f, 0.f}, 0, 0, 0);
      }
      branch(sf, vf, mx2, ls2, o2);
    }
    __syncthreads();
  }

  // epilogue: normalize, diff-combine, RMSNorm over 64 dims, write bf16
  f32x4 res[4];
  f32x4 ssq = {0.f, 0.f, 0.f, 0.f};
#pragma unroll
  for (int jn = 0; jn < 4; ++jn)
#pragma unroll
    for (int c = 0; c < 4; ++c) {
      float a1 = o1[jn][c] / ls1[c];
      float a2 = o2[jn][c] / ls2[c];
      float v = a1 - lam * a2;
      res[jn][c] = v;
      ssq[c] += v * v;
    }
#pragma unroll
  for (int d = 1; d < 16; d <<= 1) ssq += vshfl_xor(ssq, d);
  f32x4 inv;
#pragma unroll
  for (int c = 0; c < 4; ++c) inv[c] = rsqrtf(ssq[c] * (1.f / 64.f) + 1e-6f);
#pragma unroll
  for (int jn = 0; jn < 4; ++jn) {
    float sc = rms_scale[jn * 16 + l15] * ONE_MINUS_LAMBDA_INIT;
#pragma unroll
    for (int c = 0; c < 4; ++c) {
      size_t orow = row0 + qt * 64 + wid * 16 + lhi * 4 + c;
      y[orow * 1024 + head * 64 + jn * 16 + l15] = f2bf(res[jn][c] * inv[c] * sc);
    }
  }
}

// ---------------------------------------------------------------------------
extern "C" void kernel_launch(void* const* d_in, const int* in_sizes, int n_in,
                              void* d_out, int out_size, void* d_ws, size_t ws_size,
                              hipStream_t stream) {
  const float* x     = (const float*)d_in[0];
  const float* Wqkv  = (const float*)d_in[1];
  const float* Wproj = (const float*)d_in[2];
  const float* lq1   = (const float*)d_in[3];
  const float* lk1   = (const float*)d_in[4];
  const float* lq2   = (const float*)d_in[5];
  const float* lk2   = (const float*)d_in[6];
  const float* rms   = (const float*)d_in[7];
  float* out = (float*)d_out;

  char* ws = (char*)d_ws;
  u16* xb     = (u16*)(ws);                        //  8 MB  [4096][1024]
  u16* WqkvT  = (u16*)(ws + (size_t)(8  << 20));   //  6 MB  [3072][1024]
  u16* WprojT = (u16*)(ws + (size_t)(14 << 20));   //  2 MB  [1024][1024]
  u16* qkvb   = (u16*)(ws + (size_t)(16 << 20));   // 24 MB  [4096][3072]
  u16* yb     = xb;                                //  reuse: xb dead after qkv GEMM

  conv_x_kernel<<<4096, 256, 0, stream>>>(x, xb, 1048576);
  conv_transpose_kernel<<<dim3(48, 16), 256, 0, stream>>>(Wqkv, WqkvT, 1024, 3072);
  conv_transpose_kernel<<<dim3(16, 16), 256, 0, stream>>>(Wproj, WprojT, 1024, 1024);
  gemm_bt<u16><<<dim3(32, 24), 256, 0, stream>>>(xb, WqkvT, qkvb, 4096, 3072, 1024);
  diff_attn_kernel<<<dim3(32, 32), 256, 0, stream>>>(qkvb, lq1, lk1, lq2, lk2, rms, yb);
  gemm_bt<float><<<dim3(32, 8), 256, 0, stream>>>(yb, WprojT, out, 4096, 1024, 1024);
}

// Round 3
// 242.446 us; speedup vs baseline: 1.4044x; 1.4044x over previous
//
#include <hip/hip_runtime.h>
#include <cstdint>
#include <cstddef>

// ---------------------------------------------------------------------------
// Differential attention forward, MI355X/gfx950.
// R2: attention rewritten to the m214-style structure:
//   - swapped QK^T: S^T = mfma_32x32x16(K, Q^T) -> scores lane-local per q
//   - fully in-register online softmax (no shuffle-reduce, no P LDS roundtrip)
//   - P^T -> B-frag via v_cvt_pk_bf16_f32 + v_permlane32_swap (T12)
//   - defer-max rescale (T13, THR=8), per-hi-half partial ls
//   - K LDS XOR-swizzle via pre-swizzled global source (m173), linear gload_lds
//   - V^T LDS with even-coverage swizzle (write + b128 read verified)
//   - XCD-aware block swizzle (each XCD owns whole (b,head) K/V streams)
// GEMMs/converts unchanged from R1.
// ---------------------------------------------------------------------------

typedef short bf16x8 __attribute__((ext_vector_type(8)));
typedef float f32x4  __attribute__((ext_vector_type(4)));
typedef float f32x16 __attribute__((ext_vector_type(16)));
typedef unsigned short u16;
typedef u16 u16x4v __attribute__((ext_vector_type(4)));
typedef unsigned int u32;
typedef u32 u32x2 __attribute__((ext_vector_type(2)));
typedef u32 u32x4 __attribute__((ext_vector_type(4)));

#define LAMBDA_INIT 0.35550906759096926f
#define ONE_MINUS_LAMBDA_INIT 0.6444909324090307f
#define SCORE_SCALE 0.17677669529663687f   // 1/sqrt(32)

__device__ __forceinline__ u16 f2bf(float f) {
  uint32_t u = __float_as_uint(f);
  u += 0x7fffu + ((u >> 16) & 1u);          // round-to-nearest-even
  return (u16)(u >> 16);
}

__device__ __forceinline__ void gload_lds16(const void* g, void* lds) {
  __builtin_amdgcn_global_load_lds(
      (const __attribute__((address_space(1))) void*)g,
      (__attribute__((address_space(3))) void*)lds, 16, 0, 0);
}

__device__ __forceinline__ u32 cvtpk_bf16(float lo, float hi) {
  u32 r;
  asm("v_cvt_pk_bf16_f32 %0, %1, %2" : "=v"(r) : "v"(lo), "v"(hi));
  return r;
}

// exchange value with lane^32 partner (VALU-only, no LDS pipe)
__device__ __forceinline__ float xchg32f(float v, int hi) {
  u32x2 r = __builtin_amdgcn_permlane32_swap(__float_as_uint(v), __float_as_uint(v), false, false);
  return __uint_as_float(hi ? r.x : r.y);
}

__device__ __forceinline__ float rmax16(const f32x16& v) {
  float m = v[0];
#pragma unroll
  for (int i = 1; i < 16; ++i) m = fmaxf(m, v[i]);
  return m;
}

__device__ __forceinline__ float rsum16(const f32x16& v) {
  float a = 0.f;
#pragma unroll
  for (int i = 0; i < 16; ++i) a += v[i];
  return a;
}

// ---------------------------------------------------------------------------
// elementwise fp32 -> bf16 (x)
// ---------------------------------------------------------------------------
__global__ void conv_x_kernel(const float* __restrict__ in, u16* __restrict__ out, int n4) {
  int i = blockIdx.x * blockDim.x + threadIdx.x;
  if (i < n4) {
    float4 v = ((const float4*)in)[i];
    u16x4v o;
    o.x = f2bf(v.x); o.y = f2bf(v.y); o.z = f2bf(v.z); o.w = f2bf(v.w);
    ((u16x4v*)out)[i] = o;
  }
}

// ---------------------------------------------------------------------------
// W [K][N] fp32 -> WT [N][K] bf16 (64x64 LDS tile transpose)
// ---------------------------------------------------------------------------
__global__ void conv_transpose_kernel(const float* __restrict__ W, u16* __restrict__ WT,
                                      int K, int N) {
  __shared__ u16 L[64][72];
  const int n0 = blockIdx.x * 64, k0 = blockIdx.y * 64;
#pragma unroll
  for (int i = 0; i < 16; ++i) {
    int lin = i * 256 + threadIdx.x;
    int rr = lin >> 6, cc = lin & 63;
    L[rr][cc] = f2bf(W[(size_t)(k0 + rr) * N + n0 + cc]);
  }
  __syncthreads();
#pragma unroll
  for (int i = 0; i < 16; ++i) {
    int lin = i * 256 + threadIdx.x;
    int rr = lin >> 6, cc = lin & 63;
    WT[(size_t)(n0 + rr) * K + k0 + cc] = L[cc][rr];
  }
}

// ---------------------------------------------------------------------------
// bt-GEMM (m97 structure, unchanged from R1)
// ---------------------------------------------------------------------------
template <typename OutT>
__global__ __launch_bounds__(256, 2) void gemm_bt(const u16* __restrict__ A,
                                                  const u16* __restrict__ Bt,
                                                  OutT* __restrict__ C,
                                                  int M, int N, int K) {
  __shared__ __align__(16) u16 As[2][128 * 32];
  __shared__ __align__(16) u16 Bs[2][128 * 32];
  const int wid = threadIdx.x >> 6, lane = threadIdx.x & 63;
  const int l15 = lane & 15, lhi = lane >> 4;
  const int wm = wid >> 1, wn = wid & 1;
  const int tm = blockIdx.x * 128, tn = blockIdx.y * 128;
  const int rr = lane >> 2, cb = (lane & 3) * 8;
  const int nkt = K >> 5;

  f32x4 acc[4][4];
#pragma unroll
  for (int m = 0; m < 4; ++m)
#pragma unroll
    for (int n = 0; n < 4; ++n) acc[m][n] = (f32x4){0.f, 0.f, 0.f, 0.f};

  auto stage = [&](int buf, int kt) {
#pragma unroll
    for (int i = 0; i < 2; ++i) {
      int lr = wid * 32 + i * 16;
      gload_lds16(A + (size_t)(tm + lr + rr) * K + kt * 32 + cb, &As[buf][lr * 32]);
      gload_lds16(Bt + (size_t)(tn + lr + rr) * K + kt * 32 + cb, &Bs[buf][lr * 32]);
    }
  };

  stage(0, 0);
  __syncthreads();
  int buf = 0;
  for (int kt = 0; kt < nkt; ++kt) {
    if (kt + 1 < nkt) stage(buf ^ 1, kt + 1);
    bf16x8 af[4], bfr[4];
#pragma unroll
    for (int m = 0; m < 4; ++m)
      af[m] = *(const bf16x8*)&As[buf][(wm * 64 + m * 16 + l15) * 32 + lhi * 8];
#pragma unroll
    for (int n = 0; n < 4; ++n)
      bfr[n] = *(const bf16x8*)&Bs[buf][(wn * 64 + n * 16 + l15) * 32 + lhi * 8];
#pragma unroll
    for (int m = 0; m < 4; ++m)
#pragma unroll
      for (int n = 0; n < 4; ++n)
        acc[m][n] = __builtin_amdgcn_mfma_f32_16x16x32_bf16(af[m], bfr[n], acc[m][n], 0, 0, 0);
    __syncthreads();
    buf ^= 1;
  }

#pragma unroll
  for (int m = 0; m < 4; ++m)
#pragma unroll
    for (int n = 0; n < 4; ++n)
#pragma unroll
      for (int r = 0; r < 4; ++r) {
        int row = tm + wm * 64 + m * 16 + lhi * 4 + r;
        int col = tn + wn * 64 + n * 16 + l15;
        float v = acc[m][n][r];
        if constexpr (sizeof(OutT) == 2)
          C[(size_t)row * N + col] = (OutT)f2bf(v);
        else
          C[(size_t)row * N + col] = v;
      }
}

// ---------------------------------------------------------------------------
// Fused differential flash attention + RMSNorm (m214-style, 32x32 MFMA).
// Grid: 512 blocks (1D, XCD-swizzled) = 16 q-tiles x 32 (b,head).
// Block: 256 thr = 4 waves; each wave owns 32 q rows (q = col = lane&31).
// KVBLK = 64 per iteration (2 k-tiles of 32), 32 iterations.
// LDS: K1s/K2s [64][32] (XOR-swizzled via pre-swizzled gload source),
//      VTs [64 d][72 k] (swizzled transpose).
// C-layout (m74/m101): col=lane&31, row=(reg&3)+8*(reg>>2)+4*(lane>>5).
// ---------------------------------------------------------------------------
#define KLD 32
#define VLD 72

__global__ __launch_bounds__(256, 2) void diff_attn_kernel(
    const u16* __restrict__ qkv,
    const float* __restrict__ lq1, const float* __restrict__ lk1,
    const float* __restrict__ lq2, const float* __restrict__ lk2,
    const float* __restrict__ rms_scale,
    u16* __restrict__ y) {
  __shared__ __align__(16) u16 K1s[64 * KLD];
  __shared__ __align__(16) u16 K2s[64 * KLD];
  __shared__ __align__(16) u16 VTs[64 * VLD];

  const int tid = threadIdx.x;
  const int wid = tid >> 6, lane = tid & 63;
  const int l31 = lane & 31, hi = lane >> 5;

  // XCD swizzle: linear id -> (qt, bh) such that each XCD gets contiguous work
  const int id = blockIdx.x;                 // 0..511
  const int swz = (id & 7) * 64 + (id >> 3); // m157 swizzle, 512 % 8 == 0
  const int qt = swz & 15;                   // q-tile (128 rows)
  const int bh = swz >> 4;                   // b*16 + head
  const int b = bh >> 4, head = bh & 15;
  const size_t row0 = (size_t)b * 2048;

  float d1 = 0.f, d2 = 0.f;
#pragma unroll
  for (int i = 0; i < 32; ++i) { d1 += lq1[i] * lk1[i]; d2 += lq2[i] * lk2[i]; }
  const float lam = expf(d1) - expf(d2) + LAMBDA_INIT;

  const int qrow = qt * 128 + wid * 32 + l31;    // this lane's q index
  const u16* qrp = qkv + (row0 + qrow) * 3072;
  bf16x8 q1f[2], q2f[2];
#pragma unroll
  for (int c = 0; c < 2; ++c) {
    q1f[c] = *(const bf16x8*)(qrp + head * 32 + c * 16 + hi * 8);
    q2f[c] = *(const bf16x8*)(qrp + 512 + head * 32 + c * 16 + hi * 8);
  }

  f32x16 o1[2], o2[2];
#pragma unroll
  for (int dt = 0; dt < 2; ++dt)
#pragma unroll
    for (int i = 0; i < 16; ++i) { o1[dt][i] = 0.f; o2[dt][i] = 0.f; }
  float m1 = -1e30f, m2 = -1e30f;
  float ls1 = 0.f, ls2 = 0.f;                    // own-half partial sums

  // per-branch: QK^T (swapped), in-reg softmax, pack, PV
  auto process = [&](const bf16x8* qf, const u16* Ks, const bf16x8 (*vf)[2][2],
                     float& m, float& ls, f32x16* o) {
    f32x16 s[2];
#pragma unroll
    for (int t = 0; t < 2; ++t) {
#pragma unroll
      for (int i = 0; i < 16; ++i) s[t][i] = 0.f;
      const int row = t * 32 + l31;
      const int sg = 8 * ((row >> 1) & 3);
#pragma unroll
      for (int c = 0; c < 2; ++c) {
        bf16x8 kf = *(const bf16x8*)&Ks[row * KLD + ((c * 16 + hi * 8) ^ sg)];
        s[t] = __builtin_amdgcn_mfma_f32_32x32x16_bf16(kf, qf[c], s[t], 0, 0, 0);
      }
    }
    // block max (in-lane over 32, then cross-hi)
    float pm = fmaxf(rmax16(s[0]), rmax16(s[1]));
    pm = fmaxf(pm, xchg32f(pm, hi));
    // defer-max (T13): only rescale when max grew by > 8 (raw-score domain)
    if (!__all(pm - m <= 8.0f)) {
      float mn = fmaxf(m, pm);
      float corr = __expf((m - mn) * SCORE_SCALE);
      m = mn;
      ls *= corr;
#pragma unroll
      for (int dt = 0; dt < 2; ++dt)
#pragma unroll
        for (int i = 0; i < 16; ++i) o[dt][i] *= corr;
    }
#pragma unroll
    for (int t = 0; t < 2; ++t)
#pragma unroll
      for (int i = 0; i < 16; ++i)
        s[t][i] = __expf((s[t][i] - m) * SCORE_SCALE);
    ls += rsum16(s[0]) + rsum16(s[1]);
    // pack P^T -> B-frags (8 cvt_pk + 4 permlane per 32-k tile) and PV
#pragma unroll
    for (int t = 0; t < 2; ++t) {
      u32 W[4][2];
#pragma unroll
      for (int g = 0; g < 4; ++g)
#pragma unroll
        for (int u = 0; u < 2; ++u)
          W[g][u] = cvtpk_bf16(s[t][4 * g + 2 * u], s[t][4 * g + 2 * u + 1]);
#pragma unroll
      for (int kap = 0; kap < 2; ++kap) {
        u32x2 r0 = __builtin_amdgcn_permlane32_swap(W[2 * kap][0], W[2 * kap + 1][0], false, false);
        u32x2 r1 = __builtin_amdgcn_permlane32_swap(W[2 * kap][1], W[2 * kap + 1][1], false, false);
        u32x4 words = {r0.x, r1.x, r0.y, r1.y};
        bf16x8 pB = __builtin_bit_cast(bf16x8, words);
#pragma unroll
        for (int dt = 0; dt < 2; ++dt)
          o[dt] = __builtin_amdgcn_mfma_f32_32x32x16_bf16(vf[t][kap][dt], pB, o[dt], 0, 0, 0);
      }
    }
  };

  for (int kt = 0; kt < 32; ++kt) {
    const size_t krow0 = row0 + kt * 64;
    // K1/K2 staging: linear gload_lds dest, pre-swizzled global source (m173).
    // Stored: LDS[row][c] = K[row][c ^ 8*((row>>1)&3)]
    {
      const int srow = wid * 16 + (lane >> 2);
      const int gcol = 8 * ((lane & 3) ^ ((lane >> 3) & 3));
      const u16* g = qkv + (krow0 + srow) * 3072 + 1024 + head * 32 + gcol;
      gload_lds16(g, &K1s[wid * 512]);
      gload_lds16(g + 512, &K2s[wid * 512]);
    }
    // V^T staging: 16B loads + swizzled u16 scatter (even bank coverage)
    {
#pragma unroll
      for (int h2 = 0; h2 < 2; ++h2) {
        int vid = h2 * 256 + tid;
        int vrow = vid >> 3, d0 = (vid & 7) * 8;
        bf16x8 vv = *(const bf16x8*)(qkv + (krow0 + vrow) * 3072 + 2048 + head * 64 + d0);
        int wrow = vrow ^ (d0 & 56);           // ((d0>>3)&7)<<3 == d0&56
#pragma unroll
        for (int e = 0; e < 8; ++e) VTs[(d0 + e) * VLD + wrow] = (u16)vv[e];
      }
    }
    __syncthreads();

    // hoist V A-frags (V^T), shared by both branches
    bf16x8 vf[2][2][2];
#pragma unroll
    for (int t = 0; t < 2; ++t)
#pragma unroll
      for (int kap = 0; kap < 2; ++kap)
#pragma unroll
        for (int dt = 0; dt < 2; ++dt) {
          int d = dt * 32 + l31;
          int koff = (t * 32 + kap * 16 + hi * 8) ^ ((d & 56));
          vf[t][kap][dt] = *(const bf16x8*)&VTs[d * VLD + koff];
        }

    process(q1f, K1s, vf, m1, ls1, o1);
    process(q2f, K2s, vf, m2, ls2, o2);
    __syncthreads();
  }

  // ---- epilogue: combine halves, diff, RMSNorm over 64 dims, store bf16 ----
  ls1 += xchg32f(ls1, hi);
  ls2 += xchg32f(ls2, hi);
  const float il1 = 1.0f / ls1, il2 = 1.0f / ls2;

  f32x16 v[2];
  float ssq = 0.f;
#pragma unroll
  for (int dt = 0; dt < 2; ++dt)
#pragma unroll
    for (int i = 0; i < 16; ++i) {
      float a = o1[dt][i] * il1 - lam * (o2[dt][i] * il2);
      v[dt][i] = a;
      ssq += a * a;
    }
  ssq += xchg32f(ssq, hi);
  const float inv = rsqrtf(ssq * (1.0f / 64.0f) + 1e-6f);

  u16* yr = y + (row0 + qrow) * 1024 + head * 64;
#pragma unroll
  for (int dt = 0; dt < 2; ++dt)
#pragma unroll
    for (int rg = 0; rg < 4; ++rg) {
      int dbase = 8 * rg + 4 * hi + 32 * dt;
      u16x4v w;
#pragma unroll
      for (int bb = 0; bb < 4; ++bb)
        w[bb] = f2bf(v[dt][4 * rg + bb] * inv * rms_scale[dbase + bb] * ONE_MINUS_LAMBDA_INIT);
      *(u16x4v*)(yr + dbase) = w;
    }
}

// ---------------------------------------------------------------------------
extern "C" void kernel_launch(void* const* d_in, const int* in_sizes, int n_in,
                              void* d_out, int out_size, void* d_ws, size_t ws_size,
                              hipStream_t stream) {
  const float* x     = (const float*)d_in[0];
  const float* Wqkv  = (const float*)d_in[1];
  const float* Wproj = (const float*)d_in[2];
  const float* lq1   = (const float*)d_in[3];
  const float* lk1   = (const float*)d_in[4];
  const float* lq2   = (const float*)d_in[5];
  const float* lk2   = (const float*)d_in[6];
  const float* rms   = (const float*)d_in[7];
  float* out = (float*)d_out;

  char* ws = (char*)d_ws;
  u16* xb     = (u16*)(ws);                        //  8 MB  [4096][1024]
  u16* WqkvT  = (u16*)(ws + (size_t)(8  << 20));   //  6 MB  [3072][1024]
  u16* WprojT = (u16*)(ws + (size_t)(14 << 20));   //  2 MB  [1024][1024]
  u16* qkvb   = (u16*)(ws + (size_t)(16 << 20));   // 24 MB  [4096][3072]
  u16* yb     = xb;                                //  reuse: xb dead after qkv GEMM

  conv_x_kernel<<<4096, 256, 0, stream>>>(x, xb, 1048576);
  conv_transpose_kernel<<<dim3(48, 16), 256, 0, stream>>>(Wqkv, WqkvT, 1024, 3072);
  conv_transpose_kernel<<<dim3(16, 16), 256, 0, stream>>>(Wproj, WprojT, 1024, 1024);
  gemm_bt<u16><<<dim3(32, 24), 256, 0, stream>>>(xb, WqkvT, qkvb, 4096, 3072, 1024);
  diff_attn_kernel<<<512, 256, 0, stream>>>(qkvb, lq1, lk1, lq2, lk2, rms, yb);
  gemm_bt<float><<<dim3(32, 8), 256, 0, stream>>>(yb, WprojT, out, 4096, 1024, 1024);
}